// Round 15
// baseline (238.489 us; speedup 1.0000x reference)
//
#include <hip/hip_runtime.h>
#include <math.h>

#define MTOT 9216      // 96*96 pixels
#define CDIM 256
#define KSEL 20
#define NCHUNK 8
#define CHUNKQ 1152    // q pixels per chunk
#define BS 32          // s pixels per block (resident)
#define QSTEP 128      // q per step (4 waves x 2 qtiles x 16)
#define NSTEP 9        // CHUNKQ / QSTEP
#define NSLAB 36       // NSTEP * 4 k-slabs of 64

typedef __attribute__((ext_vector_type(8))) short short8;
typedef __attribute__((ext_vector_type(8))) unsigned short ushort8;
typedef __attribute__((ext_vector_type(4))) float f32x4;
typedef __attribute__((ext_vector_type(2))) _Float16 h2;

__device__ __forceinline__ unsigned short f2bf(float v) {
    unsigned u = __float_as_uint(v);
    u += 0x7FFF + ((u >> 16) & 1);          // RNE
    return (unsigned short)(u >> 16);
}
__device__ __forceinline__ h2 pkh2(float lo, float hi) {
    auto r = __builtin_amdgcn_cvt_pkrtz(lo, hi);   // v_cvt_pkrtz_f16_f32
    h2 h; __builtin_memcpy(&h, &r, 4); return h;
}
__device__ __forceinline__ h2 asH2(unsigned int u) {
    h2 h; __builtin_memcpy(&h, &u, 4); return h;
}
__device__ __forceinline__ unsigned int h2u(h2 h) {
    unsigned int u; __builtin_memcpy(&u, &h, 4); return u;
}
// forced packed f16 min/max (VOP3P) -- builtin elementwise forms scalarize
__device__ __forceinline__ h2 h2max(h2 a, h2 b) {
    h2 d; asm("v_pk_max_f16 %0, %1, %2" : "=v"(d) : "v"(a), "v"(b)); return d;
}
__device__ __forceinline__ h2 h2min(h2 a, h2 b) {
    h2 d; asm("v_pk_min_f16 %0, %1, %2" : "=v"(d) : "v"(a), "v"(b)); return d;
}
__device__ __forceinline__ unsigned short hbits(_Float16 x) {
    unsigned short u; __builtin_memcpy(&u, &x, 2); return u;
}
__device__ __forceinline__ float hs2f(unsigned short u) {
    _Float16 x; __builtin_memcpy(&x, &u, 2); return (float)x;
}

// packed dual-list insert (lists independent per half); clamped no-op if <= head
__device__ __forceinline__ void ins20p(h2 (&l)[KSEL], h2 v) {
    v = h2max(v, l[0]);
#pragma unroll
    for (int i = 0; i < KSEL - 1; ++i) {
        h2 nxt = l[i + 1];
        l[i] = h2min(nxt, v);
        v = h2max(nxt, v);
    }
    l[KSEL - 1] = v;
}
__device__ __forceinline__ void ins20(float (&l)[KSEL], float v) {
#pragma unroll
    for (int i = 0; i < KSEL - 1; ++i) {
        float nxt = l[i + 1];
        l[i] = fminf(nxt, v);
        v = fmaxf(nxt, v);
    }
    l[KSEL - 1] = v;
}

// Kernel 1: fused norms + mask/slot + normalized bf16 transpose [m][C]
__global__ __launch_bounds__(256) void prepconv_kernel(
    const int* __restrict__ ql, const int* __restrict__ color,
    const float* __restrict__ qf, const float* __restrict__ sf,
    int* __restrict__ cnt,
    unsigned short* __restrict__ qbt, unsigned short* __restrict__ sbt)
{
    __shared__ float tilef[32 * 257];
    __shared__ float red[256];
    __shared__ float invv[32];
    __shared__ int slotl[32];
    const int bid = blockIdx.x;
    const bool isQ = bid < (MTOT / 32);
    const int m0 = (isQ ? bid : bid - MTOT / 32) * 32;
    const float* src = isQ ? qf : sf;
    const int t = threadIdx.x;
    const int ml = t & 31, cb = t >> 5;
    float sq = 0.f;
#pragma unroll
    for (int i = 0; i < 32; ++i) {
        int c = cb * 32 + i;
        float v = src[c * MTOT + m0 + ml];
        tilef[ml * 257 + c] = v;
        sq += v * v;
    }
    red[cb * 32 + ml] = sq;
    __syncthreads();
    if (t < 32) {
        float s = 0.f;
#pragma unroll
        for (int j = 0; j < 8; ++j) s += red[j * 32 + t];
        invv[t] = 1.0f / fmaxf(sqrtf(s), 1e-12f);
        if (isQ) {
            int m = m0 + t;
            bool fg = (ql[3*m] == color[0]) & (ql[3*m+1] == color[1]) & (ql[3*m+2] == color[2]);
            slotl[t] = fg ? atomicAdd(&cnt[0], 1) : (MTOT - 1 - atomicAdd(&cnt[1], 1));
        }
    }
    __syncthreads();
    const int row = t >> 3, seg = t & 7;
    const float iv = invv[row];
    const int drow = isQ ? slotl[row] : (m0 + row);
    unsigned short* dst = (isQ ? qbt : sbt) + (size_t)drow * 256 + seg * 32;
    const float* srcr = &tilef[row * 257 + seg * 32];
#pragma unroll
    for (int ch = 0; ch < 4; ++ch) {
        ushort8 o;
#pragma unroll
        for (int e = 0; e < 8; ++e) o[e] = f2bf(srcr[ch * 8 + e] * iv);
        *(ushort8*)(dst + ch * 8) = o;
    }
}

// Kernel 2: C[q][s] MFMA. B (Sb) fragments HOISTED to registers once per
// block (K-resident, identical across all q-steps -> old scheme re-read them
// 9x from LDS). Main loop reads only A from wave-private Q dbuf. All slab
// indices compile-time (step loop x unrolled 4-slab body) per rule #20.
__global__ __launch_bounds__(256, 3) void matchsim_kernel(
    const unsigned short* __restrict__ qbt, const unsigned short* __restrict__ sbt,
    const int* __restrict__ cnt, unsigned short* __restrict__ part)
{
    // Sb[32][256] swz @0 (16K, used once) | Q: 2 bufs x 4 waves x 4K @16K..48K.
    // merge alias @0: u32 [2 cls][16 owner][16 sp] stride 21 -> 43008 B.
    __shared__ __align__(16) char smem[49152];
    unsigned int* mbuf = (unsigned int*)smem;

    const int t = threadIdx.x;
    const int w = t >> 6, l = t & 63;
    const int sblk = blockIdx.x >> 3;
    const int chunk = blockIdx.x & 7;
    const int s0 = sblk * BS;
    const int q0c = chunk * CHUNKQ;
    const int fgc = cnt[0];

    // stage Sb: 32 s-rows x 512 B, XOR-swizzled; the only staging barrier
    {
        int row = t >> 3, cb = t & 7;
        const ushort8* gs = (const ushort8*)(sbt + (size_t)(s0 + row) * 256);
#pragma unroll
        for (int i = 0; i < 4; ++i) {
            int ch = cb + i * 8;
            ushort8 v = gs[ch];
            int byte = (row * 512 + ch * 16) ^ ((row & 7) << 4);
            *(ushort8*)(smem + byte) = v;
        }
    }
    __syncthreads();

    // fragment addressing
    const int lg = l >> 4;                        // lane k-group
    const int aq0 = l & 15;                       // wave-local qtile0 row
    const int aq1 = aq0 + 16;
    const int aswz0 = (aq0 & 7) << 4, aswz1 = (aq1 & 7) << 4;
    const int srow0 = l & 15, srow1 = srow0 + 16; // s rows in Sb
    const int bswz0 = (srow0 & 7) << 4, bswz1 = (srow1 & 7) << 4;

    // hoist ALL B fragments: [slab][ks][srow-half] -> 16 short8 (64 VGPR),
    // fully unrolled = static indices
    short8 Bf[16];
#pragma unroll
    for (int sl = 0; sl < 4; ++sl)
#pragma unroll
        for (int ks = 0; ks < 2; ++ks) {
            int bk = sl * 128 + ks * 64 + lg * 16;
            Bf[sl * 4 + ks * 2 + 0] = *(const short8*)(smem + ((srow0 * 512 + bk) ^ bswz0));
            Bf[sl * 4 + ks * 2 + 1] = *(const short8*)(smem + ((srow1 * 512 + bk) ^ bswz1));
        }

    const h2 NEG2 = { (_Float16)-65504.f, (_Float16)-65504.f };
    h2 fgl[KSEL], bgl[KSEL];
#pragma unroll
    for (int i = 0; i < KSEL; ++i) { fgl[i] = NEG2; bgl[i] = NEG2; }

    // Q slab prefetch: 64 B per thread per slab; 2 threads cover one q-row
    const int wl = (t & 63) >> 1;                 // wave-local q row (0..31)
    const int qhalf = t & 1;
    ushort8 qr[4];                                // single stash, distance-1
    auto loadQ = [&](int gslab) {
        int step = gslab >> 2, slab = gslab & 3;
        const unsigned short* base =
            qbt + (size_t)(q0c + step * QSTEP + w * 32 + wl) * 256 + slab * 64 + qhalf * 32;
#pragma unroll
        for (int i = 0; i < 4; ++i)
            qr[i] = *(const ushort8*)(base + i * 8);
    };
    loadQ(0);
    const int qwswz = (wl & 7) << 4;
    char* const qbase = smem + 16384 + w * 4096;  // this wave's buffer-0 slice

    f32x4 acc00 = {0,0,0,0}, acc01 = {0,0,0,0}, acc10 = {0,0,0,0}, acc11 = {0,0,0,0};

    for (int step = 0; step < NSTEP; ++step) {
#pragma unroll
        for (int sl = 0; sl < 4; ++sl) {
            const int gslab = step * 4 + sl;
            char* Qs = qbase + (sl & 1) * 16384;   // dbuf parity (gslab&1 == sl&1)
            // write stash -> wave-private LDS slice (swizzled); dbuf avoids
            // same-address WAR waits in the per-wave DS pipe.
#pragma unroll
            for (int i = 0; i < 4; ++i) {
                int byte = (wl * 128 + qhalf * 64 + i * 16) ^ qwswz;
                *(ushort8*)(Qs + byte) = qr[i];
            }
            if (gslab + 1 < NSLAB) loadQ(gslab + 1);   // distance-1 refill
            __builtin_amdgcn_s_setprio(1);
#pragma unroll
            for (int ks = 0; ks < 2; ++ks) {
                int ak = ks * 64 + lg * 16;
                short8 a0 = *(const short8*)(Qs + ((aq0 * 128 + ak) ^ aswz0));
                short8 a1 = *(const short8*)(Qs + ((aq1 * 128 + ak) ^ aswz1));
                acc00 = __builtin_amdgcn_mfma_f32_16x16x32_bf16(a0, Bf[sl*4+ks*2+0], acc00, 0, 0, 0);
                acc01 = __builtin_amdgcn_mfma_f32_16x16x32_bf16(a0, Bf[sl*4+ks*2+1], acc01, 0, 0, 0);
                acc10 = __builtin_amdgcn_mfma_f32_16x16x32_bf16(a1, Bf[sl*4+ks*2+0], acc10, 0, 0, 0);
                acc11 = __builtin_amdgcn_mfma_f32_16x16x32_bf16(a1, Bf[sl*4+ks*2+1], acc11, 0, 0, 0);
            }
            __builtin_amdgcn_s_setprio(0);
        }
        // selection from registers: pair (s0+sp, s0+16+sp) per value
        const int qw0 = q0c + step * QSTEP + w * 32;
#pragma unroll
        for (int qt = 0; qt < 2; ++qt) {
            const f32x4& aS0 = qt ? acc10 : acc00;
            const f32x4& aS1 = qt ? acc11 : acc01;
            int qfirst = qw0 + qt * 16;
            if (qfirst + 16 <= fgc) {
#pragma unroll
                for (int r = 0; r < 4; ++r) ins20p(fgl, pkh2(aS0[r], aS1[r]));
            } else if (qfirst >= fgc) {
#pragma unroll
                for (int r = 0; r < 4; ++r) ins20p(bgl, pkh2(aS0[r], aS1[r]));
            } else {    // boundary 16-q window (at most one per grid)
#pragma unroll
                for (int r = 0; r < 4; ++r) {
                    h2 v = pkh2(aS0[r], aS1[r]);
                    bool m = (qfirst + lg * 4 + r) < fgc;
                    ins20p(fgl, m ? v : NEG2);
                    ins20p(bgl, m ? NEG2 : v);
                }
            }
        }
        acc00 = (f32x4){0,0,0,0}; acc01 = (f32x4){0,0,0,0};
        acc10 = (f32x4){0,0,0,0}; acc11 = (f32x4){0,0,0,0};
    }

    __syncthreads();   // all Sb/Qs use done before mbuf aliases smem
    // dump: (cls, owner, sp) stride 21 words
    const int sp = l & 15, owner = w * 4 + lg;
    auto midx = [](int cls, int own, int spi) { return ((cls * 16 + own) * 16 + spi) * 21; };
    {
        unsigned int* df = &mbuf[midx(0, owner, sp)];
        unsigned int* db = &mbuf[midx(1, owner, sp)];
#pragma unroll
        for (int k = 0; k < KSEL; ++k) { df[k] = h2u(fgl[k]); db[k] = h2u(bgl[k]); }
    }
    __syncthreads();
    auto mergeL = [&](unsigned int* A, const unsigned int* B) {
        h2 la[KSEL];
#pragma unroll
        for (int k = 0; k < KSEL; ++k) la[k] = asH2(A[k]);
        for (int j = KSEL - 1; j >= 0; --j) {
            h2 v = asH2(B[j]);
            if (!(v.x > la[0].x || v.y > la[0].y)) break;
            ins20p(la, v);
        }
#pragma unroll
        for (int k = 0; k < KSEL; ++k) A[k] = h2u(la[k]);
    };
    {   // 16 -> 8 owners
        int cls = t >> 7, u = t & 127, spi = u & 15, j = u >> 4;
        mergeL(&mbuf[midx(cls, j, spi)], &mbuf[midx(cls, j + 8, spi)]);
    }
    __syncthreads();
    if (t < 128) {
        int cls = t >> 6, u = t & 63, spi = u & 15, j = u >> 4;
        mergeL(&mbuf[midx(cls, j, spi)], &mbuf[midx(cls, j + 4, spi)]);
    }
    __syncthreads();
    if (t < 64) {
        int cls = t >> 5, u = t & 31, spi = u & 15, j = u >> 4;
        mergeL(&mbuf[midx(cls, j, spi)], &mbuf[midx(cls, j + 2, spi)]);
    }
    __syncthreads();
    if (t < 32) {   // final merge + part write (.x -> s0+sp, .y -> s0+16+sp)
        int cls = t >> 4, spi = t & 15;
        unsigned int* A = &mbuf[midx(cls, 0, spi)];
        const unsigned int* B = &mbuf[midx(cls, 1, spi)];
        h2 la[KSEL];
#pragma unroll
        for (int k = 0; k < KSEL; ++k) la[k] = asH2(A[k]);
        for (int j = KSEL - 1; j >= 0; --j) {
            h2 v = asH2(B[j]);
            if (!(v.x > la[0].x || v.y > la[0].y)) break;
            ins20p(la, v);
        }
        unsigned short* d0 = &part[((size_t)(s0 + spi)      * NCHUNK + chunk) * (2*KSEL) + cls*KSEL];
        unsigned short* d1 = &part[((size_t)(s0 + 16 + spi) * NCHUNK + chunk) * (2*KSEL) + cls*KSEL];
#pragma unroll
        for (int k = 0; k < KSEL; ++k) {
            d0[k] = hbits(la[k].x);
            d1[k] = hbits(la[k].y);
        }
    }
}

// Kernel 3: merge NCHUNK chunk-lists per row per class -> mean (f32)
__global__ __launch_bounds__(256) void finalize_kernel(
    const unsigned short* __restrict__ part, float* __restrict__ out)
{
    int n = blockIdx.x * 256 + threadIdx.x;
    if (n >= MTOT) return;
    const unsigned short* base = part + (size_t)n * NCHUNK * 2 * KSEL;
#pragma unroll
    for (int cls = 0; cls < 2; ++cls) {
        float la[KSEL];
        const unsigned short* c0p = base + cls * KSEL;
#pragma unroll
        for (int k = 0; k < KSEL; ++k) la[k] = hs2f(c0p[k]);
        for (int ch = 1; ch < NCHUNK; ++ch) {
            const unsigned short* sp = base + ch * 2 * KSEL + cls * KSEL;
            for (int j = KSEL - 1; j >= 0; --j) {
                float v = hs2f(sp[j]);
                if (v <= la[0]) break;
                ins20(la, v);
            }
        }
        float s = 0.f;
#pragma unroll
        for (int k = 0; k < KSEL; ++k) s += la[k];
        out[cls * MTOT + n] = s * (1.0f / KSEL);
    }
}

extern "C" void kernel_launch(void* const* d_in, const int* in_sizes, int n_in,
                              void* d_out, int out_size, void* d_ws, size_t ws_size,
                              hipStream_t stream) {
    const int*   ql    = (const int*)d_in[0];
    const int*   color = (const int*)d_in[1];
    const float* qf    = (const float*)d_in[2];
    const float* sf    = (const float*)d_in[3];
    float* out = (float*)d_out;

    // ws: cnt[4] | qbt bf16[9216*256] | sbt bf16[9216*256] | part u16[9216*8*40]
    int* cnt = (int*)d_ws;
    unsigned short* qbt = (unsigned short*)(cnt + 4);
    unsigned short* sbt = qbt + (size_t)MTOT * CDIM;
    unsigned short* part = sbt + (size_t)MTOT * CDIM;

    (void)hipMemsetAsync(cnt, 0, 16, stream);
    prepconv_kernel<<<2 * (MTOT / 32), 256, 0, stream>>>(ql, color, qf, sf, cnt, qbt, sbt);
    matchsim_kernel<<<(MTOT / BS) * NCHUNK, 256, 0, stream>>>(qbt, sbt, cnt, part);
    finalize_kernel<<<MTOT / 256, 256, 0, stream>>>(part, out);
}

// Round 16
// 180.153 us; speedup vs baseline: 1.3238x; 1.3238x over previous
//
#include <hip/hip_runtime.h>
#include <math.h>

#define MTOT 9216      // 96*96 pixels
#define CDIM 256
#define KSEL 20
#define NCHUNK 8
#define CHUNKQ 1152    // q pixels per chunk
#define BS 32          // s pixels per block (resident)
#define QSTEP 128      // q per step (4 waves x 2 qtiles x 16)
#define NSTEP 9        // CHUNKQ / QSTEP
#define NSLAB 36       // NSTEP * 4 k-slabs of 64

typedef __attribute__((ext_vector_type(8))) short short8;
typedef __attribute__((ext_vector_type(8))) unsigned short ushort8;
typedef __attribute__((ext_vector_type(4))) float f32x4;
typedef __attribute__((ext_vector_type(2))) _Float16 h2;

__device__ __forceinline__ unsigned short f2bf(float v) {
    unsigned u = __float_as_uint(v);
    u += 0x7FFF + ((u >> 16) & 1);          // RNE
    return (unsigned short)(u >> 16);
}
__device__ __forceinline__ h2 pkh2(float lo, float hi) {
    auto r = __builtin_amdgcn_cvt_pkrtz(lo, hi);   // v_cvt_pkrtz_f16_f32
    h2 h; __builtin_memcpy(&h, &r, 4); return h;
}
__device__ __forceinline__ h2 asH2(unsigned int u) {
    h2 h; __builtin_memcpy(&h, &u, 4); return h;
}
__device__ __forceinline__ unsigned int h2u(h2 h) {
    unsigned int u; __builtin_memcpy(&u, &h, 4); return u;
}
// forced packed f16 min/max (VOP3P) -- builtin elementwise forms scalarize
__device__ __forceinline__ h2 h2max(h2 a, h2 b) {
    h2 d; asm("v_pk_max_f16 %0, %1, %2" : "=v"(d) : "v"(a), "v"(b)); return d;
}
__device__ __forceinline__ h2 h2min(h2 a, h2 b) {
    h2 d; asm("v_pk_min_f16 %0, %1, %2" : "=v"(d) : "v"(a), "v"(b)); return d;
}
__device__ __forceinline__ unsigned short hbits(_Float16 x) {
    unsigned short u; __builtin_memcpy(&u, &x, 2); return u;
}
__device__ __forceinline__ float hs2f(unsigned short u) {
    _Float16 x; __builtin_memcpy(&x, &u, 2); return (float)x;
}

// packed dual-list insert (lists independent per half); clamped no-op if <= head
__device__ __forceinline__ void ins20p(h2 (&l)[KSEL], h2 v) {
    v = h2max(v, l[0]);
#pragma unroll
    for (int i = 0; i < KSEL - 1; ++i) {
        h2 nxt = l[i + 1];
        l[i] = h2min(nxt, v);
        v = h2max(nxt, v);
    }
    l[KSEL - 1] = v;
}
__device__ __forceinline__ void ins20(float (&l)[KSEL], float v) {
#pragma unroll
    for (int i = 0; i < KSEL - 1; ++i) {
        float nxt = l[i + 1];
        l[i] = fminf(nxt, v);
        v = fmaxf(nxt, v);
    }
    l[KSEL - 1] = v;
}

// Kernel 1: fused norms + mask/slot + normalized bf16 transpose [m][C]
__global__ __launch_bounds__(256) void prepconv_kernel(
    const int* __restrict__ ql, const int* __restrict__ color,
    const float* __restrict__ qf, const float* __restrict__ sf,
    int* __restrict__ cnt,
    unsigned short* __restrict__ qbt, unsigned short* __restrict__ sbt)
{
    __shared__ float tilef[32 * 257];
    __shared__ float red[256];
    __shared__ float invv[32];
    __shared__ int slotl[32];
    const int bid = blockIdx.x;
    const bool isQ = bid < (MTOT / 32);
    const int m0 = (isQ ? bid : bid - MTOT / 32) * 32;
    const float* src = isQ ? qf : sf;
    const int t = threadIdx.x;
    const int ml = t & 31, cb = t >> 5;
    float sq = 0.f;
#pragma unroll
    for (int i = 0; i < 32; ++i) {
        int c = cb * 32 + i;
        float v = src[c * MTOT + m0 + ml];
        tilef[ml * 257 + c] = v;
        sq += v * v;
    }
    red[cb * 32 + ml] = sq;
    __syncthreads();
    if (t < 32) {
        float s = 0.f;
#pragma unroll
        for (int j = 0; j < 8; ++j) s += red[j * 32 + t];
        invv[t] = 1.0f / fmaxf(sqrtf(s), 1e-12f);
        if (isQ) {
            int m = m0 + t;
            bool fg = (ql[3*m] == color[0]) & (ql[3*m+1] == color[1]) & (ql[3*m+2] == color[2]);
            slotl[t] = fg ? atomicAdd(&cnt[0], 1) : (MTOT - 1 - atomicAdd(&cnt[1], 1));
        }
    }
    __syncthreads();
    const int row = t >> 3, seg = t & 7;
    const float iv = invv[row];
    const int drow = isQ ? slotl[row] : (m0 + row);
    unsigned short* dst = (isQ ? qbt : sbt) + (size_t)drow * 256 + seg * 32;
    const float* srcr = &tilef[row * 257 + seg * 32];
#pragma unroll
    for (int ch = 0; ch < 4; ++ch) {
        ushort8 o;
#pragma unroll
        for (int e = 0; e < 8; ++e) o[e] = f2bf(srcr[ch * 8 + e] * iv);
        *(ushort8*)(dst + ch * 8) = o;
    }
}

// Kernel 2 (R14 verbatim -- best measured 152 us): C[q][s] MFMA; wave-private
// Q LDS double-buffer, zero main-loop barriers; forced-packed f16 selection;
// distance-2 dual-stash prefetch. NOTE (R15): hoisting B fragments to 64 VGPR
// spills the top-20 lists (82 MB scratch) -- do not.
__global__ __launch_bounds__(256, 3) void matchsim_kernel(
    const unsigned short* __restrict__ qbt, const unsigned short* __restrict__ sbt,
    const int* __restrict__ cnt, unsigned short* __restrict__ part)
{
    // Sb[32][256] swz @0 (16K) | Q: 2 bufs x 4 waves x 4K @16K..48K.
    // merge alias @0: u32 [2 cls][16 owner][16 sp] stride 21 -> 43008 B.
    __shared__ __align__(16) char smem[49152];
    unsigned int* mbuf = (unsigned int*)smem;

    const int t = threadIdx.x;
    const int w = t >> 6, l = t & 63;
    const int sblk = blockIdx.x >> 3;
    const int chunk = blockIdx.x & 7;
    const int s0 = sblk * BS;
    const int q0c = chunk * CHUNKQ;
    const int fgc = cnt[0];

    // stage Sb: 32 s-rows x 512 B, XOR-swizzled; the only staging barrier
    {
        int row = t >> 3, cb = t & 7;
        const ushort8* gs = (const ushort8*)(sbt + (size_t)(s0 + row) * 256);
#pragma unroll
        for (int i = 0; i < 4; ++i) {
            int ch = cb + i * 8;
            ushort8 v = gs[ch];
            int byte = (row * 512 + ch * 16) ^ ((row & 7) << 4);
            *(ushort8*)(smem + byte) = v;
        }
    }
    __syncthreads();

    const h2 NEG2 = { (_Float16)-65504.f, (_Float16)-65504.f };
    h2 fgl[KSEL], bgl[KSEL];
#pragma unroll
    for (int i = 0; i < KSEL; ++i) { fgl[i] = NEG2; bgl[i] = NEG2; }

    // Q slab prefetch: 64 B per thread per slab; 2 threads cover one q-row
    const int wl = (t & 63) >> 1;                 // wave-local q row (0..31)
    const int qhalf = t & 1;
    auto loadQ = [&](int gslab, ushort8 (&dst)[4]) {
        int step = gslab >> 2, slab = gslab & 3;
        const unsigned short* base =
            qbt + (size_t)(q0c + step * QSTEP + w * 32 + wl) * 256 + slab * 64 + qhalf * 32;
#pragma unroll
        for (int i = 0; i < 4; ++i)
            dst[i] = *(const ushort8*)(base + i * 8);
    };
    ushort8 qrA[4], qrB[4];
    loadQ(0, qrA);
    loadQ(1, qrB);
    const int qwswz = (wl & 7) << 4;
    char* const qbase = smem + 16384 + w * 4096;  // this wave's buffer-0 slice

    // fragment addressing
    const int lg = l >> 4;                        // lane k-group
    const int aq0 = l & 15;                       // wave-local qtile0 row
    const int aq1 = aq0 + 16;
    const int aswz0 = (aq0 & 7) << 4, aswz1 = (aq1 & 7) << 4;
    const int srow0 = l & 15, srow1 = srow0 + 16; // s rows in Sb
    const int bswz0 = (srow0 & 7) << 4, bswz1 = (srow1 & 7) << 4;

    f32x4 acc00 = {0,0,0,0}, acc01 = {0,0,0,0}, acc10 = {0,0,0,0}, acc11 = {0,0,0,0};
    int cur = 0;

    auto slabBody = [&](int gslab, ushort8 (&stash)[4]) {
        char* Qs = qbase + cur * 16384;
        // write prefetched slab -> wave-private LDS slice (swizzled); dbuf
        // avoids same-address write-after-read waits in the per-wave DS pipe.
#pragma unroll
        for (int i = 0; i < 4; ++i) {
            int byte = (wl * 128 + qhalf * 64 + i * 16) ^ qwswz;
            *(ushort8*)(Qs + byte) = stash[i];
        }
        if (gslab + 2 < NSLAB) loadQ(gslab + 2, stash);   // distance-2 refill
        const int slab = gslab & 3;
        __builtin_amdgcn_s_setprio(1);
#pragma unroll
        for (int ks = 0; ks < 2; ++ks) {
            int ak = ks * 64 + lg * 16;
            short8 a0 = *(const short8*)(Qs + ((aq0 * 128 + ak) ^ aswz0));
            short8 a1 = *(const short8*)(Qs + ((aq1 * 128 + ak) ^ aswz1));
            int bk = slab * 128 + ks * 64 + lg * 16;
            short8 b0 = *(const short8*)(smem + ((srow0 * 512 + bk) ^ bswz0));
            short8 b1 = *(const short8*)(smem + ((srow1 * 512 + bk) ^ bswz1));
            acc00 = __builtin_amdgcn_mfma_f32_16x16x32_bf16(a0, b0, acc00, 0, 0, 0);
            acc01 = __builtin_amdgcn_mfma_f32_16x16x32_bf16(a0, b1, acc01, 0, 0, 0);
            acc10 = __builtin_amdgcn_mfma_f32_16x16x32_bf16(a1, b0, acc10, 0, 0, 0);
            acc11 = __builtin_amdgcn_mfma_f32_16x16x32_bf16(a1, b1, acc11, 0, 0, 0);
        }
        __builtin_amdgcn_s_setprio(0);
        cur ^= 1;
        if (slab == 3) {
            // selection from registers: pair (s0+sp, s0+16+sp) per value
            const int step = gslab >> 2;
            const int qw0 = q0c + step * QSTEP + w * 32;
#pragma unroll
            for (int qt = 0; qt < 2; ++qt) {
                const f32x4& aS0 = qt ? acc10 : acc00;
                const f32x4& aS1 = qt ? acc11 : acc01;
                int qfirst = qw0 + qt * 16;
                if (qfirst + 16 <= fgc) {
#pragma unroll
                    for (int r = 0; r < 4; ++r) ins20p(fgl, pkh2(aS0[r], aS1[r]));
                } else if (qfirst >= fgc) {
#pragma unroll
                    for (int r = 0; r < 4; ++r) ins20p(bgl, pkh2(aS0[r], aS1[r]));
                } else {    // boundary 16-q window (at most one per grid)
#pragma unroll
                    for (int r = 0; r < 4; ++r) {
                        h2 v = pkh2(aS0[r], aS1[r]);
                        bool m = (qfirst + lg * 4 + r) < fgc;
                        ins20p(fgl, m ? v : NEG2);
                        ins20p(bgl, m ? NEG2 : v);
                    }
                }
            }
            acc00 = (f32x4){0,0,0,0}; acc01 = (f32x4){0,0,0,0};
            acc10 = (f32x4){0,0,0,0}; acc11 = (f32x4){0,0,0,0};
        }
    };

    for (int gs = 0; gs < NSLAB; gs += 2) {
        slabBody(gs,     qrA);
        slabBody(gs + 1, qrB);
    }

    __syncthreads();   // all Sb/Qs use done before mbuf aliases smem
    // dump: (cls, owner, sp) stride 21 words
    const int sp = l & 15, owner = w * 4 + lg;
    auto midx = [](int cls, int own, int spi) { return ((cls * 16 + own) * 16 + spi) * 21; };
    {
        unsigned int* df = &mbuf[midx(0, owner, sp)];
        unsigned int* db = &mbuf[midx(1, owner, sp)];
#pragma unroll
        for (int k = 0; k < KSEL; ++k) { df[k] = h2u(fgl[k]); db[k] = h2u(bgl[k]); }
    }
    __syncthreads();
    auto mergeL = [&](unsigned int* A, const unsigned int* B) {
        h2 la[KSEL];
#pragma unroll
        for (int k = 0; k < KSEL; ++k) la[k] = asH2(A[k]);
        for (int j = KSEL - 1; j >= 0; --j) {
            h2 v = asH2(B[j]);
            if (!(v.x > la[0].x || v.y > la[0].y)) break;
            ins20p(la, v);
        }
#pragma unroll
        for (int k = 0; k < KSEL; ++k) A[k] = h2u(la[k]);
    };
    {   // 16 -> 8 owners
        int cls = t >> 7, u = t & 127, spi = u & 15, j = u >> 4;
        mergeL(&mbuf[midx(cls, j, spi)], &mbuf[midx(cls, j + 8, spi)]);
    }
    __syncthreads();
    if (t < 128) {
        int cls = t >> 6, u = t & 63, spi = u & 15, j = u >> 4;
        mergeL(&mbuf[midx(cls, j, spi)], &mbuf[midx(cls, j + 4, spi)]);
    }
    __syncthreads();
    if (t < 64) {
        int cls = t >> 5, u = t & 31, spi = u & 15, j = u >> 4;
        mergeL(&mbuf[midx(cls, j, spi)], &mbuf[midx(cls, j + 2, spi)]);
    }
    __syncthreads();
    if (t < 32) {   // final merge + part write (.x -> s0+sp, .y -> s0+16+sp)
        int cls = t >> 4, spi = t & 15;
        unsigned int* A = &mbuf[midx(cls, 0, spi)];
        const unsigned int* B = &mbuf[midx(cls, 1, spi)];
        h2 la[KSEL];
#pragma unroll
        for (int k = 0; k < KSEL; ++k) la[k] = asH2(A[k]);
        for (int j = KSEL - 1; j >= 0; --j) {
            h2 v = asH2(B[j]);
            if (!(v.x > la[0].x || v.y > la[0].y)) break;
            ins20p(la, v);
        }
        unsigned short* d0 = &part[((size_t)(s0 + spi)      * NCHUNK + chunk) * (2*KSEL) + cls*KSEL];
        unsigned short* d1 = &part[((size_t)(s0 + 16 + spi) * NCHUNK + chunk) * (2*KSEL) + cls*KSEL];
#pragma unroll
        for (int k = 0; k < KSEL; ++k) {
            d0[k] = hbits(la[k].x);
            d1[k] = hbits(la[k].y);
        }
    }
}

// Kernel 3: merge NCHUNK chunk-lists -> mean. Parallel over (row, class):
// 18432 work items (was 9216 doing 2 classes serially).
__global__ __launch_bounds__(256) void finalize_kernel(
    const unsigned short* __restrict__ part, float* __restrict__ out)
{
    int idx = blockIdx.x * 256 + threadIdx.x;
    if (idx >= 2 * MTOT) return;
    int n = idx >> 1, cls = idx & 1;
    const unsigned short* base = part + (size_t)n * NCHUNK * 2 * KSEL + cls * KSEL;
    float la[KSEL];
#pragma unroll
    for (int k = 0; k < KSEL; ++k) la[k] = hs2f(base[k]);
    for (int ch = 1; ch < NCHUNK; ++ch) {
        const unsigned short* sp = base + ch * 2 * KSEL;
        for (int j = KSEL - 1; j >= 0; --j) {
            float v = hs2f(sp[j]);
            if (v <= la[0]) break;
            ins20(la, v);
        }
    }
    float s = 0.f;
#pragma unroll
    for (int k = 0; k < KSEL; ++k) s += la[k];
    out[cls * MTOT + n] = s * (1.0f / KSEL);
}

extern "C" void kernel_launch(void* const* d_in, const int* in_sizes, int n_in,
                              void* d_out, int out_size, void* d_ws, size_t ws_size,
                              hipStream_t stream) {
    const int*   ql    = (const int*)d_in[0];
    const int*   color = (const int*)d_in[1];
    const float* qf    = (const float*)d_in[2];
    const float* sf    = (const float*)d_in[3];
    float* out = (float*)d_out;

    // ws: cnt[4] | qbt bf16[9216*256] | sbt bf16[9216*256] | part u16[9216*8*40]
    int* cnt = (int*)d_ws;
    unsigned short* qbt = (unsigned short*)(cnt + 4);
    unsigned short* sbt = qbt + (size_t)MTOT * CDIM;
    unsigned short* part = sbt + (size_t)MTOT * CDIM;

    (void)hipMemsetAsync(cnt, 0, 16, stream);
    prepconv_kernel<<<2 * (MTOT / 32), 256, 0, stream>>>(ql, color, qf, sf, cnt, qbt, sbt);
    matchsim_kernel<<<(MTOT / BS) * NCHUNK, 256, 0, stream>>>(qbt, sbt, cnt, part);
    finalize_kernel<<<(2 * MTOT + 255) / 256, 256, 0, stream>>>(part, out);
}